// Round 8
// baseline (129.910 us; speedup 1.0000x reference)
//
#include <hip/hip_runtime.h>

#define HW    4096
#define CDIM  64
#define KCB   1024
#define NELM  8388608
#define NPTS  131072
#define NBLKA 1024         // 512 point-groups x 2 codebook halves
#define NBLKB 512

typedef __attribute__((ext_vector_type(8))) short  short8;
typedef __attribute__((ext_vector_type(4))) float  float4v;

__device__ inline unsigned short f2bf(float v) {
    unsigned u = __builtin_bit_cast(unsigned, v);
    unsigned r = u + 0x7FFF + ((u >> 16) & 1);   // RNE
    return (unsigned short)(r >> 16);
}
__device__ inline unsigned umin32(unsigned a, unsigned b) { return a < b ? a : b; }

// ws: [0..1023] e_sq+1.0 | [1024] accum | [1025] ticket | [2048..] cbB bf16 -2*cb frag-order
//     [67584..] pmin u32 per point (131072)
__global__ void vq_prep(const float* __restrict__ cb, float* __restrict__ esqb,
                        float* __restrict__ accum, int* __restrict__ cnt,
                        unsigned short* __restrict__ cbB, unsigned* __restrict__ pmin) {
    int u = blockIdx.x * 256 + threadIdx.x;      // 0..131071
    pmin[u] = 0xFFFFFFFFu;
    if (u == 0) { *accum = 0.0f; *cnt = 0; }
    if (u < KCB) {
        const float* row = cb + u * CDIM;
        float s = 0.0f;
        #pragma unroll
        for (int c = 0; c < CDIM; ++c) s = fmaf(row[c], row[c], s);
        esqb[u] = s + 1.0f;                      // +1 bias => packed distances strictly positive
    }
    if (u < 8192) {                              // B-frag order (verified R2-R7); B = -2*e
        int k = u >> 3, s7 = u & 7;
        const float* src = cb + k * CDIM + s7 * 8;
        unsigned short tmp[8];
        #pragma unroll
        for (int j = 0; j < 8; ++j) tmp[j] = f2bf(-2.0f * src[j]);
        int kt = k >> 4, n = k & 15, f = s7 >> 2, q = s7 & 3;
        int dst = (((kt * 2 + f) * 64) + q * 16 + n) * 8;
        *(short8*)(cbB + dst) = *(short8*)tmp;
    }
}

// Kernel A: 256 points x 512 codes per block; 2 blocks/CU resident.
__global__ __launch_bounds__(512, 4)   // 4 waves/EU -> 2 blocks/CU, VGPR cap 128
void vq_argmin(const float* __restrict__ x,
               const float* __restrict__ esqb,
               const unsigned short* __restrict__ cbB,
               unsigned* __restrict__ pmin,
               float* __restrict__ accum) {
    __shared__ unsigned short bbuf[512 * 64];    // 64 KB: half codebook, frag order
    __shared__ float lesq[512];                  // 2 KB
    __shared__ float wred[8];

    const int t    = threadIdx.x;                // 0..511, 8 waves
    const int half = blockIdx.x & 1;
    const int n0   = (blockIdx.x >> 1) * 256;    // point base
    const int b    = n0 >> 12;
    const int hw0  = n0 & (HW - 1);
    const int l    = t & 63, w = t >> 6;
    const int col  = l & 15, q = l >> 4;
    const int p0   = w * 32;

    // ---- stage half codebook (64 KB) into LDS: 8 rounds x 512 thr x 16 B ----
    const unsigned short* gsrc = cbB + half * 32768;
    #pragma unroll
    for (int i = 0; i < 8; ++i) {
        int off = (i * 512 + t) * 8;             // shorts
        __builtin_amdgcn_global_load_lds(
            (const __attribute__((address_space(1))) unsigned int*)(gsrc + off),
            (__attribute__((address_space(3))) unsigned int*)(&bbuf[off]),
            16, 0, 0);
    }
    lesq[t] = esqb[half * 512 + t];

    // ---- A fragments direct from global (overlaps staging): 32 pts/wave ----
    short8 a[2][2];
    float  xs = 0.0f;
    const float* xbase = x + (size_t)b * CDIM * HW + hw0;
    #pragma unroll
    for (int mt = 0; mt < 2; ++mt) {
        const int p = p0 + mt * 16 + col;
        #pragma unroll
        for (int f = 0; f < 2; ++f) {
            unsigned short tmp[8];
            #pragma unroll
            for (int j = 0; j < 8; ++j) {
                float v = xbase[(size_t)(f * 32 + q * 8 + j) * HW + p];
                xs = fmaf(v, v, xs);
                tmp[j] = f2bf(v);
            }
            a[mt][f] = *(short8*)tmp;
        }
    }
    __syncthreads();   // bbuf + lesq resident

    // ---- k-loop: 32 kts; 2-kt named-register pipeline; ev issued before B ----
    unsigned bm[8];
    #pragma unroll
    for (int i = 0; i < 8; ++i) bm[i] = 0xFFFFFFFFu;
    unsigned cand = (unsigned)(half * 512 + col);
    const short8* bl = ((const short8*)bbuf) + l;

    auto kt_body = [&](short8 b0, short8 b1, float ev) {
        float4v c0 = {ev, ev, ev, ev};
        #pragma unroll
        for (int mt = 0; mt < 2; ++mt) {
            float4v acc = __builtin_amdgcn_mfma_f32_16x16x32_bf16(a[mt][0], b0, c0, 0, 0, 0);
            acc = __builtin_amdgcn_mfma_f32_16x16x32_bf16(a[mt][1], b1, acc, 0, 0, 0);
            #pragma unroll
            for (int r = 0; r < 4; ++r) {
                unsigned pk = (__builtin_bit_cast(unsigned, acc[r]) & 0xFFFFFC00u) | cand;
                bm[mt * 4 + r] = umin32(bm[mt * 4 + r], pk);
            }
        }
        cand += 16;
    };

    float  E0 = lesq[col],            E1 = lesq[16 + col];
    short8 A0 = bl[0],   A1 = bl[64];
    short8 A2 = bl[128], A3 = bl[192];
    for (int kt = 0; kt < 32; kt += 2) {
        short8 t0 = A0, t1 = A1, t2 = A2, t3 = A3;
        float  e0 = E0, e1 = E1;
        if (kt + 2 < 32) {
            E0 = lesq[(kt + 2) * 16 + col];      // ev first: fine-grained lgkm
            E1 = lesq[(kt + 3) * 16 + col];
            A0 = bl[(kt + 2) * 128];  A1 = bl[(kt + 2) * 128 + 64];
            A2 = bl[(kt + 3) * 128];  A3 = bl[(kt + 3) * 128 + 64];
        }
        kt_body(t0, t1, e0);
        kt_body(t2, t3, e1);
    }

    // ---- argmin across the 16 code-columns (packed butterfly) ----
    #pragma unroll
    for (int s = 1; s < 16; s <<= 1)
        #pragma unroll
        for (int i = 0; i < 8; ++i) {
            unsigned o = (unsigned)__shfl_xor((int)bm[i], s, 64);
            bm[i] = umin32(bm[i], o);
        }

    // combine across the two codebook halves: one atomicMin per point
    if (col == 0) {
        #pragma unroll
        for (int mt = 0; mt < 2; ++mt)
            #pragma unroll
            for (int r = 0; r < 4; ++r)
                atomicMin(&pmin[n0 + p0 + mt * 16 + q * 4 + r], bm[mt * 4 + r]);
    }

    // ---- x_sq contribution (exact, once per point: half 0 only) ----
    if (half == 0) {
        float lp = xs;
        #pragma unroll
        for (int off = 32; off > 0; off >>= 1) lp += __shfl_down(lp, off, 64);
        if (l == 0) wred[w] = lp;
        __syncthreads();
        if (t == 0) {
            float s = 0.0f;
            #pragma unroll
            for (int i = 0; i < 8; ++i) s += wred[i];
            atomicAdd(accum, s);
        }
    }
}

// Kernel B: z_q scatter + loss finalize. 256 points per block.
__global__ __launch_bounds__(256)
void vq_scatter(const float* __restrict__ cb,
                const unsigned* __restrict__ pmin,
                float* __restrict__ zq,
                float* __restrict__ accum,
                int* __restrict__ cnt,
                float* __restrict__ loss_out) {
    __shared__ float zbuf[CDIM * 257];           // [c*257 + pt], conflict-free
    __shared__ float wredb[4];

    const int t   = threadIdx.x;                 // 0..255
    const int n0  = blockIdx.x * 256;
    const int b   = n0 >> 12;
    const int hw0 = n0 & (HW - 1);

    const unsigned u = pmin[n0 + t];
    const int idx = (int)(u & 1023u);
    float dm1 = __builtin_bit_cast(float, u & 0xFFFFFC00u) - 1.0f;  // best(e_sq - 2dot)

    // gather exact fp32 winning row -> zbuf (channel-major)
    const float4v* crow = (const float4v*)(cb + (size_t)idx * CDIM);
    #pragma unroll
    for (int i = 0; i < 16; ++i) {
        float4v vv = crow[i];
        #pragma unroll
        for (int j = 0; j < 4; ++j) zbuf[(i * 4 + j) * 257 + t] = vv[j];
    }

    // loss partial
    #pragma unroll
    for (int off = 32; off > 0; off >>= 1) dm1 += __shfl_down(dm1, off, 64);
    if ((t & 63) == 0) wredb[t >> 6] = dm1;
    __syncthreads();

    if (t == 0) atomicAdd(accum, wredb[0] + wredb[1] + wredb[2] + wredb[3]);

    // coalesced z_q stores
    float* zp = zq + (size_t)b * CDIM * HW + hw0 + t;
    #pragma unroll
    for (int c = 0; c < CDIM; ++c)
        zp[(size_t)c * HW] = zbuf[c * 257 + t];

    // ticket: last block writes the loss
    if (t == 0) {
        __threadfence();
        int tk = atomicAdd(cnt, 1);
        if (tk == NBLKB - 1) {
            float tot = atomicAdd(accum, 0.0f);
            loss_out[0] = 1.25f * tot * (1.0f / (float)NELM);
        }
    }
}

extern "C" void kernel_launch(void* const* d_in, const int* in_sizes, int n_in,
                              void* d_out, int out_size, void* d_ws, size_t ws_size,
                              hipStream_t stream) {
    const float* x  = (const float*)d_in[0];
    const float* cb = (const float*)d_in[1];
    float* esqb  = (float*)d_ws;
    float* accum = esqb + KCB;
    int*   cnt   = (int*)(esqb + KCB + 1);
    unsigned short* cbB = (unsigned short*)(esqb + 2048);   // 128 KB
    unsigned* pmin = (unsigned*)(esqb + 2048 + 32768 + 32768); // after cbB
    float* zq   = (float*)d_out;
    float* loss = zq + NELM;

    vq_prep   <<<NPTS / 256, 256, 0, stream>>>(cb, esqb, accum, cnt, cbB, pmin);
    vq_argmin <<<NBLKA, 512, 0, stream>>>(x, esqb, cbB, pmin, accum);
    vq_scatter<<<NBLKB, 256, 0, stream>>>(cb, pmin, zq, accum, cnt, loss);
}